// Round 5
// baseline (2538.449 us; speedup 1.0000x reference)
//
#include <hip/hip_runtime.h>
#include <math.h>

#define B_DIM 2048
#define V_DIM 4096
#define H_DIM 1024
#define KC 384          // OpenBLAS SGEMM_DEFAULT_Q — panel size, frozen (bit-exactness)

#define NPANELS_H ((V_DIM + KC - 1) / KC)   // 11
#define NPANELS_V ((H_DIM + KC - 1) / KC)   // 3

enum { ACC_NONE = 0, ACC_PREACT = 1, ACC_BIAS = 2 };

// ---------------------------------------------------------------------------
// NEW PATH: split-K panel kernels (128x128 tile, 8x8 microtile) + ordered
// combine. Bit-exactness: each panel partial is the same strictly-k-ascending
// sequential fmaf chain from 0.0f as round-3/4; the combine folds panels in
// ascending-p order with plain fp32 adds (identical to tot += part).
// ---------------------------------------------------------------------------
#define PBM 128
#define PBN 128
#define PBK 16
#define ASTRIDE 20    // [x][k] tiles: 20 floats = 80 B, 16B-aligned, <=2-way conflicts
#define BSTRIDE 132   // [k][x] tiles: 132 floats = 528 B, 16B-aligned, <=2-way conflicts

// partial[p][b][j] += A-tile x W-tile over k in panel p.  C[b,j]=sum A[b,k]W[k,j]
__global__ __launch_bounds__(256, 4) void gemm_h_panel(
    const float* __restrict__ A,   // [B_DIM][V_DIM]
    const float* __restrict__ W,   // [V_DIM][H_DIM]
    float* __restrict__ P)         // [NPANELS_H][B_DIM][H_DIM]
{
    __shared__ float As[PBM][ASTRIDE];   // [row][k]
    __shared__ float Bs[PBK][BSTRIDE];   // [k][col]

    const int p    = blockIdx.z;
    const int k_lo = p * KC;
    const int k_ext = (k_lo + KC <= V_DIM) ? KC : (V_DIM - k_lo);
    const int bn = blockIdx.x * PBN;
    const int bm = blockIdx.y * PBM;
    const int t  = threadIdx.x;
    const int tx = t & 15;    // col group
    const int ty = t >> 4;    // row group (0..15)

    const int arow = t >> 1, ak = (t & 1) * 8;       // A staging: 2 float4/thread
    const int bk   = t >> 4, bc = (t & 15) * 8;      // B staging: 2 float4/thread

    float acc[8][8];
#pragma unroll
    for (int i = 0; i < 8; i++)
#pragma unroll
        for (int j = 0; j < 8; j++) acc[i][j] = 0.0f;

    const float* Abase = A + (size_t)(bm + arow) * V_DIM + k_lo + ak;
    const float* Wbase = W + (size_t)(k_lo + bk) * H_DIM + bn + bc;

    const int niter = k_ext / PBK;
    for (int it = 0; it < niter; ++it) {
        float4 a0 = *(const float4*)(Abase + it * 16);
        float4 a1 = *(const float4*)(Abase + it * 16 + 4);
        float4 b0 = *(const float4*)(Wbase + (size_t)it * 16 * H_DIM);
        float4 b1 = *(const float4*)(Wbase + (size_t)it * 16 * H_DIM + 4);
        __syncthreads();
        *(float4*)&As[arow][ak]     = a0;
        *(float4*)&As[arow][ak + 4] = a1;
        *(float4*)&Bs[bk][bc]       = b0;
        *(float4*)&Bs[bk][bc + 4]   = b1;
        __syncthreads();
#pragma unroll
        for (int kg = 0; kg < 4; kg++) {
            float ag[8][4];
#pragma unroll
            for (int i = 0; i < 4; i++) {
                float4 lo = *(const float4*)&As[ty * 4 + i][kg * 4];
                float4 hi = *(const float4*)&As[64 + ty * 4 + i][kg * 4];
                ag[i][0] = lo.x; ag[i][1] = lo.y; ag[i][2] = lo.z; ag[i][3] = lo.w;
                ag[4 + i][0] = hi.x; ag[4 + i][1] = hi.y; ag[4 + i][2] = hi.z; ag[4 + i][3] = hi.w;
            }
#pragma unroll
            for (int kk = 0; kk < 4; kk++) {
                float4 bl = *(const float4*)&Bs[kg * 4 + kk][tx * 4];
                float4 bh2 = *(const float4*)&Bs[kg * 4 + kk][tx * 4 + 64];
                float bb[8] = {bl.x, bl.y, bl.z, bl.w, bh2.x, bh2.y, bh2.z, bh2.w};
#pragma unroll
                for (int ri = 0; ri < 8; ri++) {
                    float av = ag[ri][kk];
#pragma unroll
                    for (int cj = 0; cj < 8; cj++)
                        acc[ri][cj] = fmaf(av, bb[cj], acc[ri][cj]);
                }
            }
        }
    }

    float* Pp = P + (size_t)p * B_DIM * H_DIM;
#pragma unroll
    for (int ri = 0; ri < 8; ri++) {
        const int row = bm + ((ri < 4) ? (ty * 4 + ri) : (64 + ty * 4 + ri - 4));
        float4 q0 = {acc[ri][0], acc[ri][1], acc[ri][2], acc[ri][3]};
        float4 q1 = {acc[ri][4], acc[ri][5], acc[ri][6], acc[ri][7]};
        *(float4*)(Pp + (size_t)row * H_DIM + bn + tx * 4)      = q0;
        *(float4*)(Pp + (size_t)row * H_DIM + bn + tx * 4 + 64) = q1;
    }
}

// C[b,i] = sum_k A[b,k] * W[i,k]  (h @ W^T)
__global__ __launch_bounds__(256, 4) void gemm_v_panel(
    const float* __restrict__ A,   // [B_DIM][H_DIM]
    const float* __restrict__ W,   // [V_DIM][H_DIM]
    float* __restrict__ P)         // [NPANELS_V][B_DIM][V_DIM]
{
    __shared__ float As[PBK][BSTRIDE];   // [k][row]  (A transposed in LDS)
    __shared__ float Bs[PBN][ASTRIDE];   // [col][k]

    const int p    = blockIdx.z;
    const int k_lo = p * KC;
    const int k_ext = (k_lo + KC <= H_DIM) ? KC : (H_DIM - k_lo);
    const int bn = blockIdx.x * PBN;   // over V (output cols = W rows)
    const int bm = blockIdx.y * PBM;   // over B
    const int t  = threadIdx.x;
    const int tx = t & 15;    // row group
    const int ty = t >> 4;    // col group

    const int arow = t >> 1, ak = (t & 1) * 8;
    const int bcol = t >> 1, bkq = (t & 1) * 8;

    float acc[8][8];   // [ri][cj]: rows tx-side, cols ty-side
#pragma unroll
    for (int i = 0; i < 8; i++)
#pragma unroll
        for (int j = 0; j < 8; j++) acc[i][j] = 0.0f;

    const float* Abase = A + (size_t)(bm + arow) * H_DIM + k_lo + ak;
    const float* Wbase = W + (size_t)(bn + bcol) * H_DIM + k_lo + bkq;

    const int niter = k_ext / PBK;
    for (int it = 0; it < niter; ++it) {
        float4 a0 = *(const float4*)(Abase + it * 16);
        float4 a1 = *(const float4*)(Abase + it * 16 + 4);
        float4 b0 = *(const float4*)(Wbase + it * 16);
        float4 b1 = *(const float4*)(Wbase + it * 16 + 4);
        __syncthreads();
        // A: transpose-scatter (b32 writes; 2-way conflicts only)
        As[ak + 0][arow] = a0.x; As[ak + 1][arow] = a0.y;
        As[ak + 2][arow] = a0.z; As[ak + 3][arow] = a0.w;
        As[ak + 4][arow] = a1.x; As[ak + 5][arow] = a1.y;
        As[ak + 6][arow] = a1.z; As[ak + 7][arow] = a1.w;
        *(float4*)&Bs[bcol][bkq]     = b0;
        *(float4*)&Bs[bcol][bkq + 4] = b1;
        __syncthreads();
#pragma unroll
        for (int kg = 0; kg < 4; kg++) {
            float bg[8][4];
#pragma unroll
            for (int i = 0; i < 4; i++) {
                float4 lo = *(const float4*)&Bs[ty * 4 + i][kg * 4];
                float4 hi = *(const float4*)&Bs[64 + ty * 4 + i][kg * 4];
                bg[i][0] = lo.x; bg[i][1] = lo.y; bg[i][2] = lo.z; bg[i][3] = lo.w;
                bg[4 + i][0] = hi.x; bg[4 + i][1] = hi.y; bg[4 + i][2] = hi.z; bg[4 + i][3] = hi.w;
            }
#pragma unroll
            for (int kk = 0; kk < 4; kk++) {
                float4 al = *(const float4*)&As[kg * 4 + kk][tx * 4];
                float4 ah = *(const float4*)&As[kg * 4 + kk][tx * 4 + 64];
                float aa[8] = {al.x, al.y, al.z, al.w, ah.x, ah.y, ah.z, ah.w};
#pragma unroll
                for (int cj = 0; cj < 8; cj++) {
                    float bv2 = bg[cj][kk];
#pragma unroll
                    for (int ri = 0; ri < 8; ri++)
                        acc[ri][cj] = fmaf(aa[ri], bv2, acc[ri][cj]);
                }
            }
        }
    }

    float* Pp = P + (size_t)p * B_DIM * V_DIM;
#pragma unroll
    for (int ri = 0; ri < 8; ri++) {
        const int row = bm + ((ri < 4) ? (tx * 4 + ri) : (64 + tx * 4 + ri - 4));
        float4 q0 = {acc[ri][0], acc[ri][1], acc[ri][2], acc[ri][3]};
        float4 q1 = {acc[ri][4], acc[ri][5], acc[ri][6], acc[ri][7]};
        *(float4*)(Pp + (size_t)row * V_DIM + bn + ty * 4)      = q0;
        *(float4*)(Pp + (size_t)row * V_DIM + bn + ty * 4 + 64) = q1;
    }
}

// Fold panels in order (tot=0; tot+=P[p] — identical to round-4's KC folding),
// then bias+sigmoid+sample; optional per-row fp64 score accumulation.
__global__ __launch_bounds__(256) void combine_h(
    const float* __restrict__ P, const float* __restrict__ bh,
    const float* __restrict__ U, float* __restrict__ Hout,
    double* __restrict__ acc, const int mode)
{
    const int row = blockIdx.x;
    const int c = threadIdx.x * 4;   // 256*4 = 1024 = H_DIM
    float tot[4] = {0.f, 0.f, 0.f, 0.f};
    for (int p = 0; p < NPANELS_H; p++) {
        float4 q = *(const float4*)(P + ((size_t)p * B_DIM + row) * H_DIM + c);
        tot[0] += q.x; tot[1] += q.y; tot[2] += q.z; tot[3] += q.w;
    }
    float4 bias = *(const float4*)(bh + c);
    float4 u4 = *(const float4*)(U + (size_t)row * H_DIM + c);
    float bb[4] = {bias.x, bias.y, bias.z, bias.w};
    float uu[4] = {u4.x, u4.y, u4.z, u4.w};
    float hh[4];
    double racc = 0.0;
#pragma unroll
    for (int j = 0; j < 4; j++) {
        float pre = bb[j] + tot[j];
        float pp = 1.0f / (1.0f + expf(-pre));
        hh[j] = (pp > uu[j]) ? 1.0f : 0.0f;
        if (mode == ACC_PREACT) racc += (double)hh[j] * (double)pre;
        else if (mode == ACC_BIAS) racc += (double)hh[j] * (double)bb[j];
    }
    float4 hv = {hh[0], hh[1], hh[2], hh[3]};
    *(float4*)(Hout + (size_t)row * H_DIM + c) = hv;

    if (mode != ACC_NONE) {
#pragma unroll
        for (int off = 32; off >= 1; off >>= 1) racc += __shfl_xor(racc, off, 64);
        __shared__ double red[4];
        if ((threadIdx.x & 63) == 0) red[threadIdx.x >> 6] = racc;
        __syncthreads();
        if (threadIdx.x == 0) acc[row] = ((red[0] + red[1]) + red[2]) + red[3];
    }
}

__global__ __launch_bounds__(256) void combine_v(
    const float* __restrict__ P, const float* __restrict__ bv,
    const float* __restrict__ U, float* __restrict__ Vout,
    double* __restrict__ acc, const int mode)
{
    const int row = blockIdx.x;
    double racc = 0.0;
    for (int jj = 0; jj < 4; jj++) {
        const int c = (jj * 256 + threadIdx.x) * 4;   // 4096 = V_DIM
        float tot[4] = {0.f, 0.f, 0.f, 0.f};
        for (int p = 0; p < NPANELS_V; p++) {
            float4 q = *(const float4*)(P + ((size_t)p * B_DIM + row) * V_DIM + c);
            tot[0] += q.x; tot[1] += q.y; tot[2] += q.z; tot[3] += q.w;
        }
        float4 bias = *(const float4*)(bv + c);
        float4 u4 = *(const float4*)(U + (size_t)row * V_DIM + c);
        float bb[4] = {bias.x, bias.y, bias.z, bias.w};
        float uu[4] = {u4.x, u4.y, u4.z, u4.w};
        float vvv[4];
#pragma unroll
        for (int j = 0; j < 4; j++) {
            float pre = bb[j] + tot[j];
            float pp = 1.0f / (1.0f + expf(-pre));
            vvv[j] = (pp > uu[j]) ? 1.0f : 0.0f;
            if (mode == ACC_PREACT) racc += (double)vvv[j] * (double)pre;
        }
        float4 vv4 = {vvv[0], vvv[1], vvv[2], vvv[3]};
        *(float4*)(Vout + (size_t)row * V_DIM + c) = vv4;
    }
    if (mode != ACC_NONE) {
#pragma unroll
        for (int off = 32; off >= 1; off >>= 1) racc += __shfl_xor(racc, off, 64);
        __shared__ double red[4];
        if ((threadIdx.x & 63) == 0) red[threadIdx.x >> 6] = racc;
        __syncthreads();
        if (threadIdx.x == 0) acc[row] = ((red[0] + red[1]) + red[2]) + red[3];
    }
}

// ---------------------------------------------------------------------------
// OLD PATH (round-4, passing): fallback if ws_size is too small.
// ---------------------------------------------------------------------------
#define BM 64
#define BN 64
#define BK 16
#define LDS_STRIDE 68

__global__ __launch_bounds__(256) void gemm_h_kernel(
    const float* __restrict__ A, const float* __restrict__ W,
    const float* __restrict__ bh, const float* __restrict__ U,
    float* __restrict__ Hout, double* __restrict__ acc, const int mode)
{
    __shared__ float As[2][BK][LDS_STRIDE];
    __shared__ float Bs[2][BK][LDS_STRIDE];
    const int bn = blockIdx.x * BN;
    const int bm = blockIdx.y * BM;
    const int t  = threadIdx.x;
    const int tx = t & 15, ty = t >> 4;
    const int ar = t >> 2, ac4 = t & 3;
    const int br = t >> 4, bc4 = t & 15;

    float tot[4][4], part[4][4];
#pragma unroll
    for (int i = 0; i < 4; i++)
#pragma unroll
        for (int j = 0; j < 4; j++) { tot[i][j] = 0.0f; part[i][j] = 0.0f; }

    const float* Aptr = A + (size_t)(bm + ar) * V_DIM + ac4 * 4;
    const float* Wptr = W + (size_t)bn + bc4 * 4;

    float4 av = *(const float4*)(Aptr + 0);
    float4 wv = *(const float4*)(Wptr + (size_t)br * H_DIM);
    As[0][ac4 * 4 + 0][ar] = av.x; As[0][ac4 * 4 + 1][ar] = av.y;
    As[0][ac4 * 4 + 2][ar] = av.z; As[0][ac4 * 4 + 3][ar] = av.w;
    *(float4*)(&Bs[0][br][bc4 * 4]) = wv;

    const int T = V_DIM / BK;
    int cur = 0;
    for (int it = 0; it < T; ++it) {
        __syncthreads();
        if (it + 1 < T) {
            const int k0 = (it + 1) * BK;
            av = *(const float4*)(Aptr + k0);
            wv = *(const float4*)(Wptr + (size_t)(k0 + br) * H_DIM);
        }
#pragma unroll
        for (int k = 0; k < BK; k++) {
            float4 a4 = *(const float4*)(&As[cur][k][ty * 4]);
            float4 b4 = *(const float4*)(&Bs[cur][k][tx * 4]);
            float aa[4] = {a4.x, a4.y, a4.z, a4.w};
            float bb[4] = {b4.x, b4.y, b4.z, b4.w};
#pragma unroll
            for (int i = 0; i < 4; i++)
#pragma unroll
                for (int j = 0; j < 4; j++)
                    part[i][j] = fmaf(aa[i], bb[j], part[i][j]);
        }
        if (it + 1 < T) {
            As[cur ^ 1][ac4 * 4 + 0][ar] = av.x; As[cur ^ 1][ac4 * 4 + 1][ar] = av.y;
            As[cur ^ 1][ac4 * 4 + 2][ar] = av.z; As[cur ^ 1][ac4 * 4 + 3][ar] = av.w;
            *(float4*)(&Bs[cur ^ 1][br][bc4 * 4]) = wv;
        }
        cur ^= 1;
        if ((((it + 1) * BK) % KC) == 0) {
#pragma unroll
            for (int i = 0; i < 4; i++)
#pragma unroll
                for (int j = 0; j < 4; j++) { tot[i][j] += part[i][j]; part[i][j] = 0.0f; }
        }
    }
    if ((V_DIM % KC) != 0) {
#pragma unroll
        for (int i = 0; i < 4; i++)
#pragma unroll
            for (int j = 0; j < 4; j++) tot[i][j] += part[i][j];
    }

    double rowacc[4] = {0.0, 0.0, 0.0, 0.0};
#pragma unroll
    for (int i = 0; i < 4; i++) {
        const int row = bm + ty * 4 + i;
#pragma unroll
        for (int j = 0; j < 4; j++) {
            const int col = bn + tx * 4 + j;
            float bias = bh[col];
            float pre = bias + tot[i][j];
            float p = 1.0f / (1.0f + expf(-pre));
            float u = U[(size_t)row * H_DIM + col];
            float hv = (p > u) ? 1.0f : 0.0f;
            Hout[(size_t)row * H_DIM + col] = hv;
            if (mode == ACC_PREACT) rowacc[i] += (double)hv * (double)pre;
            else if (mode == ACC_BIAS) rowacc[i] += (double)hv * (double)bias;
        }
    }
    if (mode != ACC_NONE) {
#pragma unroll
        for (int off = 8; off >= 1; off >>= 1)
#pragma unroll
            for (int i = 0; i < 4; i++)
                rowacc[i] += __shfl_xor(rowacc[i], off, 16);
        if (tx == 0) {
#pragma unroll
            for (int i = 0; i < 4; i++)
                atomicAdd(&acc[bm + ty * 4 + i], rowacc[i]);
        }
    }
}

__global__ __launch_bounds__(256) void gemm_v_kernel(
    const float* __restrict__ A, const float* __restrict__ W,
    const float* __restrict__ bv, const float* __restrict__ U,
    float* __restrict__ Vout, double* __restrict__ acc, const int mode)
{
    __shared__ float As[2][BK][LDS_STRIDE];
    __shared__ float Bs[2][BK][LDS_STRIDE];
    const int bn = blockIdx.x * BN;
    const int bm = blockIdx.y * BM;
    const int t  = threadIdx.x;
    const int tx = t & 15, ty = t >> 4;
    const int ar = t >> 2, ac4 = t & 3;

    float tot[4][4], part[4][4];
#pragma unroll
    for (int i = 0; i < 4; i++)
#pragma unroll
        for (int j = 0; j < 4; j++) { tot[i][j] = 0.0f; part[i][j] = 0.0f; }

    const float* Aptr = A + (size_t)(bm + ar) * H_DIM + ac4 * 4;
    const float* Wrow = W + (size_t)(bn + ar) * H_DIM + ac4 * 4;

    float4 av = *(const float4*)(Aptr + 0);
    float4 wv = *(const float4*)(Wrow + 0);
    As[0][ac4 * 4 + 0][ar] = av.x; As[0][ac4 * 4 + 1][ar] = av.y;
    As[0][ac4 * 4 + 2][ar] = av.z; As[0][ac4 * 4 + 3][ar] = av.w;
    Bs[0][ac4 * 4 + 0][ar] = wv.x; Bs[0][ac4 * 4 + 1][ar] = wv.y;
    Bs[0][ac4 * 4 + 2][ar] = wv.z; Bs[0][ac4 * 4 + 3][ar] = wv.w;

    const int T = H_DIM / BK;
    int cur = 0;
    for (int it = 0; it < T; ++it) {
        __syncthreads();
        if (it + 1 < T) {
            const int k0 = (it + 1) * BK;
            av = *(const float4*)(Aptr + k0);
            wv = *(const float4*)(Wrow + k0);
        }
#pragma unroll
        for (int k = 0; k < BK; k++) {
            float4 a4 = *(const float4*)(&As[cur][k][ty * 4]);
            float4 b4 = *(const float4*)(&Bs[cur][k][tx * 4]);
            float aa[4] = {a4.x, a4.y, a4.z, a4.w};
            float bb[4] = {b4.x, b4.y, b4.z, b4.w};
#pragma unroll
            for (int i = 0; i < 4; i++)
#pragma unroll
                for (int j = 0; j < 4; j++)
                    part[i][j] = fmaf(aa[i], bb[j], part[i][j]);
        }
        if (it + 1 < T) {
            As[cur ^ 1][ac4 * 4 + 0][ar] = av.x; As[cur ^ 1][ac4 * 4 + 1][ar] = av.y;
            As[cur ^ 1][ac4 * 4 + 2][ar] = av.z; As[cur ^ 1][ac4 * 4 + 3][ar] = av.w;
            Bs[cur ^ 1][ac4 * 4 + 0][ar] = wv.x; Bs[cur ^ 1][ac4 * 4 + 1][ar] = wv.y;
            Bs[cur ^ 1][ac4 * 4 + 2][ar] = wv.z; Bs[cur ^ 1][ac4 * 4 + 3][ar] = wv.w;
        }
        cur ^= 1;
        if ((((it + 1) * BK) % KC) == 0) {
#pragma unroll
            for (int i = 0; i < 4; i++)
#pragma unroll
                for (int j = 0; j < 4; j++) { tot[i][j] += part[i][j]; part[i][j] = 0.0f; }
        }
    }
    if ((H_DIM % KC) != 0) {
#pragma unroll
        for (int i = 0; i < 4; i++)
#pragma unroll
            for (int j = 0; j < 4; j++) tot[i][j] += part[i][j];
    }

    double rowacc[4] = {0.0, 0.0, 0.0, 0.0};
#pragma unroll
    for (int i = 0; i < 4; i++) {
        const int row = bm + ty * 4 + i;
#pragma unroll
        for (int j = 0; j < 4; j++) {
            const int col = bn + tx * 4 + j;
            float pre = bv[col] + tot[i][j];
            float p = 1.0f / (1.0f + expf(-pre));
            float u = U[(size_t)row * V_DIM + col];
            float vv = (p > u) ? 1.0f : 0.0f;
            Vout[(size_t)row * V_DIM + col] = vv;
            if (mode == ACC_PREACT) rowacc[i] += (double)vv * (double)pre;
        }
    }
    if (mode != ACC_NONE) {
#pragma unroll
        for (int off = 8; off >= 1; off >>= 1)
#pragma unroll
            for (int i = 0; i < 4; i++)
                rowacc[i] += __shfl_xor(rowacc[i], off, 16);
        if (tx == 0) {
#pragma unroll
            for (int i = 0; i < 4; i++)
                atomicAdd(&acc[bm + ty * 4 + i], rowacc[i]);
        }
    }
}

// ---------------------------------------------------------------------------
__global__ __launch_bounds__(256) void rowdot_kernel(
    const float* __restrict__ X, const float* __restrict__ w,
    double* __restrict__ out, const int N)
{
    const int b = blockIdx.x;
    const float* row = X + (size_t)b * N;
    double s = 0.0;
    for (int i = threadIdx.x; i < N / 4; i += blockDim.x) {
        float4 x = ((const float4*)row)[i];
        float4 ww = ((const float4*)w)[i];
        s = fma((double)x.x, (double)ww.x, s);
        s = fma((double)x.y, (double)ww.y, s);
        s = fma((double)x.z, (double)ww.z, s);
        s = fma((double)x.w, (double)ww.w, s);
    }
#pragma unroll
    for (int off = 32; off >= 1; off >>= 1) s += __shfl_xor(s, off, 64);
    __shared__ double red[4];
    if ((threadIdx.x & 63) == 0) red[threadIdx.x >> 6] = s;
    __syncthreads();
    if (threadIdx.x == 0) out[b] = red[0] + red[1] + red[2] + red[3];
}

__global__ void finalize_kernel(const double* __restrict__ vb,
                                const double* __restrict__ accpos,
                                const double* __restrict__ acchb,
                                const double* __restrict__ accneg,
                                float* __restrict__ out)
{
    int b = blockIdx.x * blockDim.x + threadIdx.x;
    if (b < B_DIM) out[b] = (float)(vb[b] + accpos[b] - acchb[b] - accneg[b]);
}

// ---------------------------------------------------------------------------
extern "C" void kernel_launch(void* const* d_in, const int* in_sizes, int n_in,
                              void* d_out, int out_size, void* d_ws, size_t ws_size,
                              hipStream_t stream) {
    (void)in_sizes; (void)n_in; (void)out_size;
    const float* visible = (const float*)d_in[0];
    const float* b_v     = (const float*)d_in[1];
    const float* b_h     = (const float*)d_in[2];
    const float* W       = (const float*)d_in[3];
    const float* u_h0    = (const float*)d_in[4];
    const float* u_v     = (const float*)d_in[5];  // [3, B, V]
    const float* u_h     = (const float*)d_in[6];  // [2, B, H]
    float* out = (float*)d_out;

    float* v_buf   = (float*)d_ws;                               // B*V floats
    float* h_buf   = v_buf + (size_t)B_DIM * V_DIM;              // B*H floats
    double* acc_pos = (double*)(h_buf + (size_t)B_DIM * H_DIM);  // B doubles
    double* acc_hb  = acc_pos + B_DIM;
    double* acc_neg = acc_hb + B_DIM;
    double* vb      = acc_neg + B_DIM;
    float* P        = (float*)(vb + B_DIM);                      // panel partials

    const size_t UV = (size_t)B_DIM * V_DIM;
    const size_t UH = (size_t)B_DIM * H_DIM;
    const size_t pmax = (size_t)NPANELS_H * UH > (size_t)NPANELS_V * UV
                            ? (size_t)NPANELS_H * UH : (size_t)NPANELS_V * UV;
    const size_t need = (UV + UH) * 4 + 4 * B_DIM * 8 + pmax * 4;

    dim3 blk(256);
    rowdot_kernel<<<B_DIM, blk, 0, stream>>>(visible, b_v, vb, V_DIM);

    if (ws_size >= need) {
        // ---- split-K panel path ----
        dim3 gph(PBN >= H_DIM ? 1 : H_DIM / PBN, B_DIM / PBM, NPANELS_H);  // 8,16,11
        dim3 gpv(V_DIM / PBN, B_DIM / PBM, NPANELS_V);                     // 32,16,3

        // positive phase
        gemm_h_panel<<<gph, blk, 0, stream>>>(visible, W, P);
        combine_h<<<B_DIM, blk, 0, stream>>>(P, b_h, u_h0, h_buf, acc_pos, ACC_PREACT);
        // k=0
        gemm_v_panel<<<gpv, blk, 0, stream>>>(h_buf, W, P);
        combine_v<<<B_DIM, blk, 0, stream>>>(P, b_v, u_v + 0 * UV, v_buf, nullptr, ACC_NONE);
        // k=1
        gemm_h_panel<<<gph, blk, 0, stream>>>(v_buf, W, P);
        combine_h<<<B_DIM, blk, 0, stream>>>(P, b_h, u_h + 0 * UH, h_buf, nullptr, ACC_NONE);
        // k=2
        gemm_v_panel<<<gpv, blk, 0, stream>>>(h_buf, W, P);
        combine_v<<<B_DIM, blk, 0, stream>>>(P, b_v, u_v + 1 * UV, v_buf, nullptr, ACC_NONE);
        // k=3
        gemm_h_panel<<<gph, blk, 0, stream>>>(v_buf, W, P);
        combine_h<<<B_DIM, blk, 0, stream>>>(P, b_h, u_h + 1 * UH, h_buf, acc_hb, ACC_BIAS);
        // k=4
        gemm_v_panel<<<gpv, blk, 0, stream>>>(h_buf, W, P);
        combine_v<<<B_DIM, blk, 0, stream>>>(P, b_v, u_v + 2 * UV, v_buf, acc_neg, ACC_PREACT);
    } else {
        // ---- fallback: round-4 fused path ----
        hipMemsetAsync(acc_pos, 0, 3 * B_DIM * sizeof(double), stream);
        dim3 gh(H_DIM / BN, B_DIM / BM);
        dim3 gv(V_DIM / BN, B_DIM / BM);
        gemm_h_kernel<<<gh, blk, 0, stream>>>(visible, W, b_h, u_h0, h_buf, acc_pos, ACC_PREACT);
        gemm_v_kernel<<<gv, blk, 0, stream>>>(h_buf, W, b_v, u_v + 0 * UV, v_buf, nullptr, ACC_NONE);
        gemm_h_kernel<<<gh, blk, 0, stream>>>(v_buf, W, b_h, u_h + 0 * UH, h_buf, nullptr, ACC_NONE);
        gemm_v_kernel<<<gv, blk, 0, stream>>>(h_buf, W, b_v, u_v + 1 * UV, v_buf, nullptr, ACC_NONE);
        gemm_h_kernel<<<gh, blk, 0, stream>>>(v_buf, W, b_h, u_h + 1 * UH, h_buf, acc_hb, ACC_BIAS);
        gemm_v_kernel<<<gv, blk, 0, stream>>>(h_buf, W, b_v, u_v + 2 * UV, v_buf, acc_neg, ACC_PREACT);
    }

    finalize_kernel<<<(B_DIM + 255) / 256, blk, 0, stream>>>(vb, acc_pos, acc_hb, acc_neg, out);
}

// Round 6
// 2471.917 us; speedup vs baseline: 1.0269x; 1.0269x over previous
//
#include <hip/hip_runtime.h>
#include <math.h>

#define B_DIM 2048
#define V_DIM 4096
#define H_DIM 1024
#define KC 384          // OpenBLAS SGEMM_DEFAULT_Q — panel size, frozen (bit-exactness)

#define NPANELS_H ((V_DIM + KC - 1) / KC)   // 11
#define NPANELS_V ((H_DIM + KC - 1) / KC)   // 3

enum { ACC_NONE = 0, ACC_PREACT = 1, ACC_BIAS = 2 };

// ---------------------------------------------------------------------------
// Split-K panel kernels (128x128 tile, 8x8 microtile) + ordered combine.
// Bit-exactness invariant (verified rounds 3-5): every output element's panel
// partial is a strictly-k-ascending sequential fmaf chain from 0.0f; the
// combine folds panels in ascending-p order with plain fp32 adds.
// Round 6: coalesced P stores in gemm_v_panel (rows on ty, cols on tx),
// bank-balanced Bs staging in gemm_h_panel, register-prefetch pipeline.
// ---------------------------------------------------------------------------
#define PBM 128
#define PBN 128
#define ASTRIDE 20    // [row][k]: stride 5 float4s -> all 8 bank-groups, optimal
#define BSTRIDE 132   // [k][col]: 33 float4s; staging patterns <=2-way (free)

// P[p][b][j] = sum_{k in panel p} A[b,k] * W[k,j]
__global__ __launch_bounds__(256, 4) void gemm_h_panel(
    const float* __restrict__ A,   // [B_DIM][V_DIM]
    const float* __restrict__ W,   // [V_DIM][H_DIM]
    float* __restrict__ P)         // [NPANELS_H][B_DIM][H_DIM]
{
    __shared__ float As[PBM][ASTRIDE];   // [b-row][k]
    __shared__ float Bs[16][BSTRIDE];    // [k][h-col]

    const int p    = blockIdx.z;
    const int k_lo = p * KC;
    const int k_ext = (k_lo + KC <= V_DIM) ? KC : (V_DIM - k_lo);
    const int bn = blockIdx.x * PBN;
    const int bm = blockIdx.y * PBM;
    const int t  = threadIdx.x;
    const int tx = t & 15;    // col group
    const int ty = t >> 4;    // row group

    const int arow = t >> 1, ak = (t & 1) * 8;   // A staging: 2 float4/thread
    const int bk   = t >> 4, bc = (t & 15) * 4;  // B staging: cols bc and bc+64

    float acc[8][8];
#pragma unroll
    for (int i = 0; i < 8; i++)
#pragma unroll
        for (int j = 0; j < 8; j++) acc[i][j] = 0.0f;

    const float* Abase = A + (size_t)(bm + arow) * V_DIM + k_lo + ak;
    const float* Wbase = W + (size_t)(k_lo + bk) * H_DIM + bn + bc;

    const int niter = k_ext / 16;
    float4 a0 = *(const float4*)(Abase);
    float4 a1 = *(const float4*)(Abase + 4);
    float4 b0 = *(const float4*)(Wbase);
    float4 b1 = *(const float4*)(Wbase + 64);

    for (int it = 0; it < niter; ++it) {
        __syncthreads();   // prior compute done reading LDS
        *(float4*)&As[arow][ak]     = a0;
        *(float4*)&As[arow][ak + 4] = a1;
        *(float4*)&Bs[bk][bc]       = b0;
        *(float4*)&Bs[bk][bc + 64]  = b1;
        __syncthreads();
        if (it + 1 < niter) {   // prefetch next tile; latency hidden by compute
            a0 = *(const float4*)(Abase + (it + 1) * 16);
            a1 = *(const float4*)(Abase + (it + 1) * 16 + 4);
            b0 = *(const float4*)(Wbase + (size_t)(it + 1) * 16 * H_DIM);
            b1 = *(const float4*)(Wbase + (size_t)(it + 1) * 16 * H_DIM + 64);
        }
#pragma unroll
        for (int kg = 0; kg < 4; kg++) {
            float ag[8][4];
#pragma unroll
            for (int i = 0; i < 4; i++) {
                float4 lo = *(const float4*)&As[ty * 4 + i][kg * 4];
                float4 hi = *(const float4*)&As[64 + ty * 4 + i][kg * 4];
                ag[i][0] = lo.x; ag[i][1] = lo.y; ag[i][2] = lo.z; ag[i][3] = lo.w;
                ag[4 + i][0] = hi.x; ag[4 + i][1] = hi.y; ag[4 + i][2] = hi.z; ag[4 + i][3] = hi.w;
            }
#pragma unroll
            for (int kk = 0; kk < 4; kk++) {
                float4 bl = *(const float4*)&Bs[kg * 4 + kk][tx * 4];
                float4 bh2 = *(const float4*)&Bs[kg * 4 + kk][tx * 4 + 64];
                float bb[8] = {bl.x, bl.y, bl.z, bl.w, bh2.x, bh2.y, bh2.z, bh2.w};
#pragma unroll
                for (int ri = 0; ri < 8; ri++) {
                    float av = ag[ri][kk];
#pragma unroll
                    for (int cj = 0; cj < 8; cj++)
                        acc[ri][cj] = fmaf(av, bb[cj], acc[ri][cj]);
                }
            }
        }
    }

    float* Pp = P + (size_t)p * B_DIM * H_DIM;
#pragma unroll
    for (int ri = 0; ri < 8; ri++) {
        const int row = bm + ((ri < 4) ? (ty * 4 + ri) : (64 + ty * 4 + ri - 4));
        float4 q0 = {acc[ri][0], acc[ri][1], acc[ri][2], acc[ri][3]};
        float4 q1 = {acc[ri][4], acc[ri][5], acc[ri][6], acc[ri][7]};
        *(float4*)(Pp + (size_t)row * H_DIM + bn + tx * 4)      = q0;
        *(float4*)(Pp + (size_t)row * H_DIM + bn + tx * 4 + 64) = q1;
    }
}

// P[p][b][i] = sum_{k in panel p} A[b,k] * W[i,k]   (h @ W^T)
// Mirror of gemm_h_panel: rows on ty, cols on tx -> coalesced P stores.
__global__ __launch_bounds__(256, 4) void gemm_v_panel(
    const float* __restrict__ A,   // [B_DIM][H_DIM]
    const float* __restrict__ W,   // [V_DIM][H_DIM]
    float* __restrict__ P)         // [NPANELS_V][B_DIM][V_DIM]
{
    __shared__ float As[PBM][ASTRIDE];   // [b-row][k]
    __shared__ float Bs[16][BSTRIDE];    // [k][v-col]

    const int p    = blockIdx.z;
    const int k_lo = p * KC;
    const int k_ext = (k_lo + KC <= H_DIM) ? KC : (H_DIM - k_lo);
    const int bn = blockIdx.x * PBN;   // over V
    const int bm = blockIdx.y * PBM;   // over B
    const int t  = threadIdx.x;
    const int tx = t & 15;    // col group
    const int ty = t >> 4;    // row group

    const int arow = t >> 1, ak = (t & 1) * 8;
    const int wcol = t >> 1, wk = (t & 1) * 8;   // W staging: transpose-scatter

    float acc[8][8];
#pragma unroll
    for (int i = 0; i < 8; i++)
#pragma unroll
        for (int j = 0; j < 8; j++) acc[i][j] = 0.0f;

    const float* Abase = A + (size_t)(bm + arow) * H_DIM + k_lo + ak;
    const float* Wbase = W + (size_t)(bn + wcol) * H_DIM + k_lo + wk;

    const int niter = k_ext / 16;
    float4 a0 = *(const float4*)(Abase);
    float4 a1 = *(const float4*)(Abase + 4);
    float4 b0 = *(const float4*)(Wbase);
    float4 b1 = *(const float4*)(Wbase + 4);

    for (int it = 0; it < niter; ++it) {
        __syncthreads();
        *(float4*)&As[arow][ak]     = a0;
        *(float4*)&As[arow][ak + 4] = a1;
        Bs[wk + 0][wcol] = b0.x; Bs[wk + 1][wcol] = b0.y;
        Bs[wk + 2][wcol] = b0.z; Bs[wk + 3][wcol] = b0.w;
        Bs[wk + 4][wcol] = b1.x; Bs[wk + 5][wcol] = b1.y;
        Bs[wk + 6][wcol] = b1.z; Bs[wk + 7][wcol] = b1.w;
        __syncthreads();
        if (it + 1 < niter) {
            a0 = *(const float4*)(Abase + (it + 1) * 16);
            a1 = *(const float4*)(Abase + (it + 1) * 16 + 4);
            b0 = *(const float4*)(Wbase + (it + 1) * 16);
            b1 = *(const float4*)(Wbase + (it + 1) * 16 + 4);
        }
#pragma unroll
        for (int kg = 0; kg < 4; kg++) {
            float ag[8][4];
#pragma unroll
            for (int i = 0; i < 4; i++) {
                float4 lo = *(const float4*)&As[ty * 4 + i][kg * 4];
                float4 hi = *(const float4*)&As[64 + ty * 4 + i][kg * 4];
                ag[i][0] = lo.x; ag[i][1] = lo.y; ag[i][2] = lo.z; ag[i][3] = lo.w;
                ag[4 + i][0] = hi.x; ag[4 + i][1] = hi.y; ag[4 + i][2] = hi.z; ag[4 + i][3] = hi.w;
            }
#pragma unroll
            for (int kk = 0; kk < 4; kk++) {
                float4 bl = *(const float4*)&Bs[kg * 4 + kk][tx * 4];
                float4 bh2 = *(const float4*)&Bs[kg * 4 + kk][tx * 4 + 64];
                float bb[8] = {bl.x, bl.y, bl.z, bl.w, bh2.x, bh2.y, bh2.z, bh2.w};
#pragma unroll
                for (int ri = 0; ri < 8; ri++) {
                    float av = ag[ri][kk];
#pragma unroll
                    for (int cj = 0; cj < 8; cj++)
                        acc[ri][cj] = fmaf(av, bb[cj], acc[ri][cj]);
                }
            }
        }
    }

    float* Pp = P + (size_t)p * B_DIM * V_DIM;
#pragma unroll
    for (int ri = 0; ri < 8; ri++) {
        const int row = bm + ((ri < 4) ? (ty * 4 + ri) : (64 + ty * 4 + ri - 4));
        float4 q0 = {acc[ri][0], acc[ri][1], acc[ri][2], acc[ri][3]};
        float4 q1 = {acc[ri][4], acc[ri][5], acc[ri][6], acc[ri][7]};
        *(float4*)(Pp + (size_t)row * V_DIM + bn + tx * 4)      = q0;
        *(float4*)(Pp + (size_t)row * V_DIM + bn + tx * 4 + 64) = q1;
    }
}

// Fold panels in ascending order (tot=0; tot+=P[p]), bias+sigmoid+sample,
// optional per-row fp64 score accumulation (non-atomic full write).
__global__ __launch_bounds__(256) void combine_h(
    const float* __restrict__ P, const float* __restrict__ bh,
    const float* __restrict__ U, float* __restrict__ Hout,
    double* __restrict__ acc, const int mode)
{
    const int row = blockIdx.x;
    const int c = threadIdx.x * 4;   // 256*4 = 1024 = H_DIM
    float tot[4] = {0.f, 0.f, 0.f, 0.f};
    for (int p = 0; p < NPANELS_H; p++) {
        float4 q = *(const float4*)(P + ((size_t)p * B_DIM + row) * H_DIM + c);
        tot[0] += q.x; tot[1] += q.y; tot[2] += q.z; tot[3] += q.w;
    }
    float4 bias = *(const float4*)(bh + c);
    float4 u4 = *(const float4*)(U + (size_t)row * H_DIM + c);
    float bb[4] = {bias.x, bias.y, bias.z, bias.w};
    float uu[4] = {u4.x, u4.y, u4.z, u4.w};
    float hh[4];
    double racc = 0.0;
#pragma unroll
    for (int j = 0; j < 4; j++) {
        float pre = bb[j] + tot[j];
        float pp = 1.0f / (1.0f + expf(-pre));
        hh[j] = (pp > uu[j]) ? 1.0f : 0.0f;
        if (mode == ACC_PREACT) racc += (double)hh[j] * (double)pre;
        else if (mode == ACC_BIAS) racc += (double)hh[j] * (double)bb[j];
    }
    float4 hv = {hh[0], hh[1], hh[2], hh[3]};
    *(float4*)(Hout + (size_t)row * H_DIM + c) = hv;

    if (mode != ACC_NONE) {
#pragma unroll
        for (int off = 32; off >= 1; off >>= 1) racc += __shfl_xor(racc, off, 64);
        __shared__ double red[4];
        if ((threadIdx.x & 63) == 0) red[threadIdx.x >> 6] = racc;
        __syncthreads();
        if (threadIdx.x == 0) acc[row] = ((red[0] + red[1]) + red[2]) + red[3];
    }
}

__global__ __launch_bounds__(256) void combine_v(
    const float* __restrict__ P, const float* __restrict__ bv,
    const float* __restrict__ U, float* __restrict__ Vout,
    double* __restrict__ acc, const int mode)
{
    const int row = blockIdx.x;
    double racc = 0.0;
    for (int jj = 0; jj < 4; jj++) {
        const int c = (jj * 256 + threadIdx.x) * 4;   // 4096 = V_DIM
        float tot[4] = {0.f, 0.f, 0.f, 0.f};
        for (int p = 0; p < NPANELS_V; p++) {
            float4 q = *(const float4*)(P + ((size_t)p * B_DIM + row) * V_DIM + c);
            tot[0] += q.x; tot[1] += q.y; tot[2] += q.z; tot[3] += q.w;
        }
        float4 bias = *(const float4*)(bv + c);
        float4 u4 = *(const float4*)(U + (size_t)row * V_DIM + c);
        float bb[4] = {bias.x, bias.y, bias.z, bias.w};
        float uu[4] = {u4.x, u4.y, u4.z, u4.w};
        float vvv[4];
#pragma unroll
        for (int j = 0; j < 4; j++) {
            float pre = bb[j] + tot[j];
            float pp = 1.0f / (1.0f + expf(-pre));
            vvv[j] = (pp > uu[j]) ? 1.0f : 0.0f;
            if (mode == ACC_PREACT) racc += (double)vvv[j] * (double)pre;
        }
        float4 vv4 = {vvv[0], vvv[1], vvv[2], vvv[3]};
        *(float4*)(Vout + (size_t)row * V_DIM + c) = vv4;
    }
    if (mode != ACC_NONE) {
#pragma unroll
        for (int off = 32; off >= 1; off >>= 1) racc += __shfl_xor(racc, off, 64);
        __shared__ double red[4];
        if ((threadIdx.x & 63) == 0) red[threadIdx.x >> 6] = racc;
        __syncthreads();
        if (threadIdx.x == 0) acc[row] = ((red[0] + red[1]) + red[2]) + red[3];
    }
}

// out[b] = sum_i X[b,i] * w[i] in fp64 (score term; does not feed sampling)
__global__ __launch_bounds__(256) void rowdot_kernel(
    const float* __restrict__ X, const float* __restrict__ w,
    double* __restrict__ out, const int N)
{
    const int b = blockIdx.x;
    const float* row = X + (size_t)b * N;
    double s = 0.0;
    for (int i = threadIdx.x; i < N / 4; i += blockDim.x) {
        float4 x = ((const float4*)row)[i];
        float4 ww = ((const float4*)w)[i];
        s = fma((double)x.x, (double)ww.x, s);
        s = fma((double)x.y, (double)ww.y, s);
        s = fma((double)x.z, (double)ww.z, s);
        s = fma((double)x.w, (double)ww.w, s);
    }
#pragma unroll
    for (int off = 32; off >= 1; off >>= 1) s += __shfl_xor(s, off, 64);
    __shared__ double red[4];
    if ((threadIdx.x & 63) == 0) red[threadIdx.x >> 6] = s;
    __syncthreads();
    if (threadIdx.x == 0) out[b] = red[0] + red[1] + red[2] + red[3];
}

__global__ void finalize_kernel(const double* __restrict__ vb,
                                const double* __restrict__ accpos,
                                const double* __restrict__ acchb,
                                const double* __restrict__ accneg,
                                float* __restrict__ out)
{
    int b = blockIdx.x * blockDim.x + threadIdx.x;
    if (b < B_DIM) out[b] = (float)(vb[b] + accpos[b] - acchb[b] - accneg[b]);
}

// ---------------------------------------------------------------------------
extern "C" void kernel_launch(void* const* d_in, const int* in_sizes, int n_in,
                              void* d_out, int out_size, void* d_ws, size_t ws_size,
                              hipStream_t stream) {
    (void)in_sizes; (void)n_in; (void)out_size; (void)ws_size;
    const float* visible = (const float*)d_in[0];
    const float* b_v     = (const float*)d_in[1];
    const float* b_h     = (const float*)d_in[2];
    const float* W       = (const float*)d_in[3];
    const float* u_h0    = (const float*)d_in[4];
    const float* u_v     = (const float*)d_in[5];  // [3, B, V]
    const float* u_h     = (const float*)d_in[6];  // [2, B, H]
    float* out = (float*)d_out;

    float* v_buf   = (float*)d_ws;                               // B*V floats
    float* h_buf   = v_buf + (size_t)B_DIM * V_DIM;              // B*H floats
    double* acc_pos = (double*)(h_buf + (size_t)B_DIM * H_DIM);  // B doubles
    double* acc_hb  = acc_pos + B_DIM;
    double* acc_neg = acc_hb + B_DIM;
    double* vb      = acc_neg + B_DIM;
    float* P        = (float*)(vb + B_DIM);                      // panel partials

    const size_t UV = (size_t)B_DIM * V_DIM;
    const size_t UH = (size_t)B_DIM * H_DIM;

    dim3 blk(256);
    dim3 gph(H_DIM / PBN, B_DIM / PBM, NPANELS_H);   // 8 x 16 x 11 = 1408
    dim3 gpv(V_DIM / PBN, B_DIM / PBM, NPANELS_V);   // 32 x 16 x 3 = 1536

    rowdot_kernel<<<B_DIM, blk, 0, stream>>>(visible, b_v, vb, V_DIM);

    // positive phase
    gemm_h_panel<<<gph, blk, 0, stream>>>(visible, W, P);
    combine_h<<<B_DIM, blk, 0, stream>>>(P, b_h, u_h0, h_buf, acc_pos, ACC_PREACT);
    // k=0
    gemm_v_panel<<<gpv, blk, 0, stream>>>(h_buf, W, P);
    combine_v<<<B_DIM, blk, 0, stream>>>(P, b_v, u_v + 0 * UV, v_buf, nullptr, ACC_NONE);
    // k=1
    gemm_h_panel<<<gph, blk, 0, stream>>>(v_buf, W, P);
    combine_h<<<B_DIM, blk, 0, stream>>>(P, b_h, u_h + 0 * UH, h_buf, nullptr, ACC_NONE);
    // k=2
    gemm_v_panel<<<gpv, blk, 0, stream>>>(h_buf, W, P);
    combine_v<<<B_DIM, blk, 0, stream>>>(P, b_v, u_v + 1 * UV, v_buf, nullptr, ACC_NONE);
    // k=3
    gemm_h_panel<<<gph, blk, 0, stream>>>(v_buf, W, P);
    combine_h<<<B_DIM, blk, 0, stream>>>(P, b_h, u_h + 1 * UH, h_buf, acc_hb, ACC_BIAS);
    // k=4
    gemm_v_panel<<<gpv, blk, 0, stream>>>(h_buf, W, P);
    combine_v<<<B_DIM, blk, 0, stream>>>(P, b_v, u_v + 2 * UV, v_buf, acc_neg, ACC_PREACT);

    finalize_kernel<<<(B_DIM + 255) / 256, blk, 0, stream>>>(vb, acc_pos, acc_hb, acc_neg, out);
}